// Round 6
// baseline (549.915 us; speedup 1.0000x reference)
//
#include <hip/hip_runtime.h>
#include <stdint.h>

// ---------------------------------------------------------------------------
// SelfAttention B=4 S=4096 E=1024, fp32 in/out, bf16 MFMA internally.
// Round 11 (over R10): A/B INSTRUMENTATION ROUND — barrier intrinsic vs
// opaque asm barrier, on real work.
//  - Four structural nulls (R0 2-barrier, 8-phase, read-once+persistent,
//    LDS symbol split) all pin at MfmaUtil ~32%, ~1700 cyc/phase. Common-
//    mode suspect H1: SIInsertWaitcnts inserts vmcnt drains before every
//    s_barrier INTRINSIC for pending LDS-DMA (global_load_lds), collapsing
//    the counted-vmcnt pipeline to depth 0 every phase (phase = ~900cy
//    latency + ~600cy MFMA = observed).
//  - Test: QK (tpb=4) split into two identical-shape dispatches:
//    A = tiles {0,1}/block, intrinsic barrier (today's kernel);
//    B = tiles {2,3}/block, asm("s_barrier") opaque to the compiler —
//    no auto-inserted waits; correctness carried by the explicit
//    vmcnt(6)/lgkmcnt(0) ledger (re-audited: every overwrite >=1 barrier
//    after last read; every read covered by FIFO vmcnt(6) at ph4/ph8).
//  - Both halves are correct -> test passes; rocprof shows A vs B direct.
//  - Everything else identical to R10.
// ---------------------------------------------------------------------------

typedef unsigned short ushort_t;
typedef unsigned int uint_t;
typedef __attribute__((ext_vector_type(8))) short short8;     // 8 bf16 = 4 VGPRs
typedef __attribute__((ext_vector_type(4))) float f32x4;      // MFMA acc

__device__ inline ushort_t f2bf(float f) {
  union { float f; unsigned u; } v; v.f = f;
  unsigned r = v.u + 0x7fffu + ((v.u >> 16) & 1u);  // RNE
  return (ushort_t)(r >> 16);
}

// ---------------------------------------------------------------------------
__global__ __launch_bounds__(256) void zero_f32(float* __restrict__ p, int n) {
  int i = blockIdx.x * 256 + threadIdx.x;
  if (i < n) p[i] = 0.0f;
}

// fp32 -> bf16 conversion, float4 loads, exact-fit grid (n4 = n/4)
__global__ __launch_bounds__(256) void cvt_f32_bf16(
    const float* __restrict__ in, ushort_t* __restrict__ out, int n4) {
  int i = blockIdx.x * 256 + threadIdx.x;
  if (i < n4) {
    float4 v = ((const float4*)in)[i];
    ushort4 o;
    o.x = f2bf(v.x); o.y = f2bf(v.y); o.z = f2bf(v.z); o.w = f2bf(v.w);
    ((ushort4*)out)[i] = o;
  }
}

// ---------------------------------------------------------------------------
// NT GEMM: C[m][n] = f( scale * sum_k A[m][k]*B[n][k] )
// A: [M x K] row-major bf16. B: [N x K] row-major bf16. Batch z folded into
// the tile list (strides sA/sB/sC in elements).
// EPI: 1 = +bias[col] (bias = z ? aux2 : aux), bf16 out   (Q&K projections)
//      2 = +bias[row], bf16 out                           (Vt)
//      3 = exp(v), bf16 out, atomicAdd row sums into lsum[z*lstride+row]
//      4 = v * (1/aux[z*lstride+row]), fp32 out           (PV, normalize)
// BAR: 0 = __builtin_amdgcn_s_barrier (compiler-visible)
//      1 = asm volatile("s_barrier") (opaque; no auto-inserted waitcnts;
//          explicit vmcnt/lgkmcnt ledger carries correctness)
// ---------------------------------------------------------------------------
#define BM 256
#define BN 256
#define BK 64

template<int EPI, int BAR>
__global__ __launch_bounds__(512, 2) void gemm_nt(
    const ushort_t* __restrict__ A, const ushort_t* __restrict__ B,
    const float* __restrict__ aux, const float* __restrict__ aux2,
    void* __restrict__ Cv,
    int K, int ldc, float scale, long sA, long sB, long sC,
    int lstride, float* __restrict__ lsum,
    int tn, int tm, int tz, int tpb, int ioff) {
  // 8 distinct slot arrays: [128 rows x 64 cols] each, chunk-swizzled:
  // slot (r,c) holds global chunk c^(r&7). 8 x 16 KiB = 128 KiB.
  __shared__ ushort_t As00[128 * 64];  // buf0 half0
  __shared__ ushort_t As01[128 * 64];  // buf0 half1
  __shared__ ushort_t As10[128 * 64];  // buf1 half0
  __shared__ ushort_t As11[128 * 64];  // buf1 half1
  __shared__ ushort_t Bs00[128 * 64];
  __shared__ ushort_t Bs01[128 * 64];
  __shared__ ushort_t Bs10[128 * 64];
  __shared__ ushort_t Bs11[128 * 64];

  const int t = threadIdx.x;
  const int lane = t & 63;
  const int wave = t >> 6;
  const int wr = wave >> 2;          // 0..1 (M waves)
  const int wc = wave & 3;           // 0..3 (N waves)
  const int lr = lane & 15;          // fragment row (m or n)
  const int quad = lane >> 4;        // 0..3

  const int Kb = K * 2;              // row stride in bytes
  const int nkt = K / BK;            // K-tiles per output tile
  const int niter = nkt >> 1;

  // staging geometry: per half-tile (128x64), 512 thr x 2 x 16B; LDS dst is
  // LINEAR (global_load_lds requirement); src col pre-swizzled c^(r&7).
  const int srow = t >> 3;                        // 0..63 (2nd load adds 64)
  const int scol = ((t & 7) ^ (srow & 7)) << 3;   // swizzled src col (elems)

  // ---- tile list: XCD-chunked persistent mapping --------------------------
  const int NT = tn * tm * tz;
  const int tmn = tn * tm;
  const bool chunked = (gridDim.x == 256) && ((NT & 255) == 0);
  const int xcd = blockIdx.x & 7, wblk = blockIdx.x >> 3;
  const int cpx = NT >> 3;

  auto calc = [&](int i, int& m0_, int& n0_, long& z_, uint_t& oa_, uint_t& ob_) {
    const int lin = chunked ? (xcd * cpx + i * 32 + wblk)
                            : ((int)blockIdx.x + i * (int)gridDim.x);
    const int zz = lin / tmn;
    const int r = lin - zz * tmn;
    const int mi = r / tn;
    const int ni = r - mi * tn;
    m0_ = mi * BM; n0_ = ni * BN; z_ = zz;
    oa_ = (uint_t)(((size_t)zz * (size_t)sA + (size_t)(m0_ + srow) * K + scol) * 2);
    ob_ = (uint_t)(((size_t)zz * (size_t)sB + (size_t)(n0_ + srow) * K + scol) * 2);
  };

  int m0, n0, m0n, n0n;
  long z, zn;
  uint_t oA_cur, oB_cur, oA_nxt, oB_nxt;
  calc(ioff, m0, n0, z, oA_cur, oB_cur);
  bool have_next = (tpb > 1);
  if (have_next) calc(ioff + 1, m0n, n0n, zn, oA_nxt, oB_nxt);
  else { m0n = m0; n0n = n0; zn = z; oA_nxt = oA_cur; oB_nxt = oB_cur; }

#define GLL(gp, lp) __builtin_amdgcn_global_load_lds( \
    (const __attribute__((address_space(1))) void*)(gp), \
    (__attribute__((address_space(3))) void*)(lp), 16, 0, 0)

  // j = K-tile index in the CURRENT tile's stream; j>=nkt -> next tile.
  // ARR: one of the 8 slot arrays; h: which 128-row half of the source tile.
#define STAGE_A(ARR, h, j) do { \
    const int j_ = (j); \
    const bool in_ = (j_ < nkt); \
    if (in_ || have_next) { \
      const uint_t o_ = (in_ ? (oA_cur + (uint_t)(j_ * 128)) \
                             : (oA_nxt + (uint_t)((j_ - nkt) * 128))) \
                        + (uint_t)((h) * 128 * Kb); \
      const char* g_ = (const char*)A + o_; \
      GLL(g_, &ARR[t * 8]); \
      GLL(g_ + (size_t)64 * Kb, &ARR[(512 + t) * 8]); } } while (0)

#define STAGE_B(ARR, h, j) do { \
    const int j_ = (j); \
    const bool in_ = (j_ < nkt); \
    if (in_ || have_next) { \
      const uint_t o_ = (in_ ? (oB_cur + (uint_t)(j_ * 128)) \
                             : (oB_nxt + (uint_t)((j_ - nkt) * 128))) \
                        + (uint_t)((h) * 128 * Kb); \
      const char* g_ = (const char*)B + o_; \
      GLL(g_, &ARR[t * 8]); \
      GLL(g_ + (size_t)64 * Kb, &ARR[(512 + t) * 8]); } } while (0)

  // LDS read offsets (elements). ks=1 flips chunk bit 2 -> offset ^ 32.
  int aoff[4], boff[2];
#pragma unroll
  for (int mi = 0; mi < 4; ++mi)
    aoff[mi] = (wr * 64 + mi * 16 + lr) * 64 + ((quad ^ (lr & 7)) << 3);
#pragma unroll
  for (int ni = 0; ni < 2; ++ni)
    boff[ni] = (wc * 32 + ni * 16 + lr) * 64 + ((quad ^ (lr & 7)) << 3);

  f32x4 acc[8][4] = {};
  short8 af[4][2];        // A fragments, current mh
  short8 bfr[2][2][2];    // [nh][ni][ks] — BOTH N-halves persist (read-once)

#define LDA(ARR) do { \
  _Pragma("unroll") for (int mi_ = 0; mi_ < 4; ++mi_) { \
    af[mi_][0] = *(const short8*)&ARR[aoff[mi_]]; \
    af[mi_][1] = *(const short8*)&ARR[aoff[mi_] ^ 32]; } } while (0)

#define LDB(ARR, nh) do { \
  _Pragma("unroll") for (int ni_ = 0; ni_ < 2; ++ni_) { \
    bfr[nh][ni_][0] = *(const short8*)&ARR[boff[ni_]]; \
    bfr[nh][ni_][1] = *(const short8*)&ARR[boff[ni_] ^ 32]; } } while (0)

#define MFMA16(mh, nh) do { \
  _Pragma("unroll") for (int mi_ = 0; mi_ < 4; ++mi_) \
  _Pragma("unroll") for (int ni_ = 0; ni_ < 2; ++ni_) { \
    acc[(mh) * 4 + mi_][(nh) * 2 + ni_] = __builtin_amdgcn_mfma_f32_16x16x32_bf16( \
        af[mi_][0], bfr[nh][ni_][0], acc[(mh) * 4 + mi_][(nh) * 2 + ni_], 0, 0, 0); \
    acc[(mh) * 4 + mi_][(nh) * 2 + ni_] = __builtin_amdgcn_mfma_f32_16x16x32_bf16( \
        af[mi_][1], bfr[nh][ni_][1], acc[(mh) * 4 + mi_][(nh) * 2 + ni_], 0, 0, 0); } } while (0)

  // BAR=1: opaque to SIInsertWaitcnts -> no auto-inserted vmcnt drains for
  // pending LDS-DMA; "memory" clobber pins program order of LDS/GLL ops.
#define BAR_SYNC do { if constexpr (BAR) asm volatile("s_barrier" ::: "memory"); \
                      else __builtin_amdgcn_s_barrier(); } while (0)

#define PH_TAIL \
  BAR_SYNC; \
  asm volatile("s_waitcnt lgkmcnt(0)" ::: "memory"); \
  __builtin_amdgcn_s_setprio(1)

#define PH_END \
  __builtin_amdgcn_s_setprio(0); \
  BAR_SYNC

#define VM6_BAR \
  __builtin_amdgcn_s_setprio(0); \
  asm volatile("s_waitcnt vmcnt(6)" ::: "memory"); \
  BAR_SYNC

  // ---- prologue: kt0 {As00,Bs00,Bs01,As01}, kt1 {As10,Bs10,Bs11};
  //      kt1's As11 is staged at iter0-ph1.
  STAGE_A(As00, 0, 0); STAGE_B(Bs00, 0, 0); STAGE_B(Bs01, 1, 0); STAGE_A(As01, 1, 0);
  STAGE_A(As10, 0, 1); STAGE_B(Bs10, 0, 1); STAGE_B(Bs11, 1, 1);
  asm volatile("s_waitcnt vmcnt(6)" ::: "memory");   // kt0 fully resident
  BAR_SYNC;

  for (int tile = 0; tile < tpb; ++tile) {
    for (int itl = 0; itl < niter; ++itl) {
      const int T = itl * 2;

      // ===== buf0 (K-tile T) =====
      // ph1: read As00 + Bs00 | stage As11 <- A1(T+1)  (gap: read ph7 prev)
      LDA(As00); LDB(Bs00, 0);
      STAGE_A(As11, 1, T + 1);
      PH_TAIL; MFMA16(0, 0); PH_END;

      // ph2: read Bs01 | stage As00 <- A0(T+2)  (As00 last read ph1)
      LDB(Bs01, 1);
      STAGE_A(As00, 0, T + 2);
      PH_TAIL; MFMA16(0, 1); PH_END;

      // ph3: read As01 | stage Bs00 <- B0(T+2)  (Bs00 last read ph1)
      LDA(As01);
      STAGE_B(Bs00, 0, T + 2);
      PH_TAIL; MFMA16(1, 0); PH_END;

      // ph4: no reads | stage Bs01 <- B1(T+2)  (Bs01 last read ph2)
      STAGE_B(Bs01, 1, T + 2);
      PH_TAIL; MFMA16(1, 1);
      VM6_BAR;   // completes ...ph1 -> buf1 (T+1) fully resident

      // ===== buf1 (K-tile T+1) =====
      // ph5: read As10 + Bs10 | stage As01 <- A1(T+2)  (As01 last read ph3)
      LDA(As10); LDB(Bs10, 0);
      STAGE_A(As01, 1, T + 2);
      PH_TAIL; MFMA16(0, 0); PH_END;

      // ph6: read Bs11 | stage As10 <- A0(T+3)  (As10 last read ph5)
      LDB(Bs11, 1);
      STAGE_A(As10, 0, T + 3);
      PH_TAIL; MFMA16(0, 1); PH_END;

      // ph7: read As11 | stage Bs10 <- B0(T+3)  (Bs10 last read ph5)
      LDA(As11);
      STAGE_B(Bs10, 0, T + 3);
      PH_TAIL; MFMA16(1, 0); PH_END;

      // ph8: no reads | stage Bs11 <- B1(T+3)  (Bs11 last read ph6)
      STAGE_B(Bs11, 1, T + 3);
      PH_TAIL; MFMA16(1, 1);
      VM6_BAR;   // completes ...ph5 -> buf0 (T+2) fully resident
    }

    // ---- epilogue for tile (m0, n0, z). No LDS use; next tile's staging is
    // already in flight and lands underneath these VALU ops + stores.
    // C/D layout: col = lane&15, row = (lane>>4)*4 + reg [m89-verified]
    {
      const float* bias = (EPI == 1 && z) ? aux2 : aux;
#pragma unroll
      for (int fm = 0; fm < 8; ++fm) {
#pragma unroll
        for (int r = 0; r < 4; ++r) {
          const int row = m0 + (fm >> 2) * 128 + wr * 64 + (fm & 3) * 16 + quad * 4 + r;
          float rs = 0.0f, rl = 0.0f;
          if (EPI == 4) rl = 1.0f / bias[(size_t)z * lstride + row];
#pragma unroll
          for (int fn = 0; fn < 4; ++fn) {
            const int col = n0 + (fn >> 1) * 128 + wc * 32 + (fn & 1) * 16 + lr;
            const size_t off = (size_t)(z * sC) + (size_t)row * ldc + col;
            float v = acc[fm][fn][r] * scale;
            if (EPI == 1) {
              ((ushort_t*)Cv)[off] = f2bf(v + bias[col]);
            } else if (EPI == 2) {
              ((ushort_t*)Cv)[off] = f2bf(v + bias[row]);
            } else if (EPI == 3) {
              float e = __expf(v);
              rs += e;
              ((ushort_t*)Cv)[off] = f2bf(e);
            } else {  // EPI == 4
              ((float*)Cv)[off] = v * rl;
            }
          }
          if (EPI == 3) {
            rs += __shfl_xor(rs, 1);
            rs += __shfl_xor(rs, 2);
            rs += __shfl_xor(rs, 4);
            rs += __shfl_xor(rs, 8);
            if (lr == 0)
              atomicAdd(&lsum[(size_t)z * lstride + row], rs);
          }
        }
      }
    }

    // ---- tile switch: shift next->cur, compute tile+2, re-zero acc.
    if (tile + 1 < tpb) {
      m0 = m0n; n0 = n0n; z = zn; oA_cur = oA_nxt; oB_cur = oB_nxt;
      if (tile + 2 < tpb) calc(ioff + tile + 2, m0n, n0n, zn, oA_nxt, oB_nxt);
      have_next = (tile + 2 < tpb);
#pragma unroll
      for (int fm = 0; fm < 8; ++fm)
#pragma unroll
        for (int fn = 0; fn < 4; ++fn)
          acc[fm][fn] = (f32x4){0.0f, 0.0f, 0.0f, 0.0f};
    }
  }
}

// ---------------------------------------------------------------------------
extern "C" void kernel_launch(void* const* d_in, const int* in_sizes, int n_in,
                              void* d_out, int out_size, void* d_ws,
                              size_t ws_size, hipStream_t stream) {
  const float* X  = (const float*)d_in[0];
  const float* Wq = (const float*)d_in[1];
  const float* bq = (const float*)d_in[2];
  const float* Wk = (const float*)d_in[3];
  const float* bk = (const float*)d_in[4];
  const float* Wv = (const float*)d_in[5];
  const float* bv = (const float*)d_in[6];
  float* out = (float*)d_out;

  const int Bn = 4, S = 4096, E = 1024;
  const long SE  = (long)S * E;       //  4,194,304
  const long BSE = (long)Bn * SE;     // 16,777,216
  const long SS  = (long)S * S;       // 16,777,216
  const long EE  = (long)E * E;       //  1,048,576

  // Batched path: P holds all 4 batches (134.2 MB, aliases dead Xb + spare).
  const size_t need_batched =
      (size_t)(4 * SS + 3 * EE + 3 * BSE) * 2 + (size_t)Bn * S * 4;
  const bool batched = ws_size >= need_batched;

  const long front = batched ? 4 * SS : BSE;  // bf16 elems reserved at base
  ushort_t* Xb  = (ushort_t*)d_ws;    // [B*S, E]   (steps 1-3)
  ushort_t* P   = (ushort_t*)d_ws;    // scores: [B,S,S] batched / [S,S] fallback
  ushort_t* Wqb = (ushort_t*)d_ws + front;
  ushort_t* Wkb = Wqb + EE;
  ushort_t* Wvb = Wkb + EE;
  ushort_t* Qw  = Wvb + EE;           // [B*S, E]
  ushort_t* Kw  = Qw + BSE;           // [B*S, E]  (contiguous after Qw!)
  ushort_t* Vt  = Kw + BSE;           // [B, E, S]  (V transposed)
  float*    l   = (float*)(Vt + BSE); // [B*S] softmax row sums

  // 0) zero the row-sum accumulator (ws re-poisoned to 0xAA every launch)
  zero_f32<<<(Bn * S) / 256, 256, 0, stream>>>(l, Bn * S);

  // 1) fp32 -> bf16
  cvt_f32_bf16<<<(int)(BSE / 1024), 256, 0, stream>>>(X, Xb, (int)(BSE / 4));
  cvt_f32_bf16<<<(int)(EE / 1024), 256, 0, stream>>>(Wq, Wqb, (int)(EE / 4));
  cvt_f32_bf16<<<(int)(EE / 1024), 256, 0, stream>>>(Wk, Wkb, (int)(EE / 4));
  cvt_f32_bf16<<<(int)(EE / 1024), 256, 0, stream>>>(Wv, Wvb, (int)(EE / 4));

  // 2) Q = X·Wq^T + bq ; K = X·Wk^T + bk  (z folded: NT = 4*64*2 = 512, tpb=2)
  gemm_nt<1, 0><<<256, 512, 0, stream>>>(
      Xb, Wqb, bq, bk, Qw, E, E, 1.0f, 0, EE, BSE, 0, nullptr,
      E / BN, Bn * S / BM, 2, 2, 0);

  // 3) Vt[b][e][t] = Wv[e]·X[b][t] + bv[e]  (NT = 16*4*4 = 256, tpb=1)
  gemm_nt<2, 0><<<256, 512, 0, stream>>>(
      Wvb, Xb, bv, nullptr, Vt, E, S, 1.0f, 0, SE, SE, 0, nullptr,
      S / BN, E / BM, Bn, 1, 0);

  if (batched) {
    // 4) P = exp(Q·K^T / 32), l[row] += rowsum  (NT = 1024) — A/B SPLIT:
    //    dispatch A: tiles {0,1}/block, intrinsic barrier (baseline)
    //    dispatch B: tiles {2,3}/block, opaque asm barrier (H1 test)
    gemm_nt<3, 0><<<256, 512, 0, stream>>>(
        Qw, Kw, nullptr, nullptr, P, E, S, 0.03125f, SE, SE, SS, S, l,
        S / BN, S / BM, Bn, 2, 0);
    gemm_nt<3, 1><<<256, 512, 0, stream>>>(
        Qw, Kw, nullptr, nullptr, P, E, S, 0.03125f, SE, SE, SS, S, l,
        S / BN, S / BM, Bn, 2, 2);
    // 5) out = (P·Vt^T) / l[row]  (NT = 4*16*4 = 256, tpb=1)
    gemm_nt<4, 0><<<256, 512, 0, stream>>>(
        P, Vt, l, nullptr, out, S, E, 1.0f, SS, SE, SE, S, nullptr,
        E / BN, S / BM, Bn, 1, 0);
  } else {
    // fallback: per-batch P (aliases dead Xb), stream-ordered reuse
    for (int b = 0; b < Bn; ++b) {
      gemm_nt<3, 0><<<256, 512, 0, stream>>>(
          Qw + b * SE, Kw + b * SE, nullptr, nullptr, P, E, S, 0.03125f,
          0, 0, 0, 0, l + b * S, S / BN, S / BM, 1, 1, 0);
      gemm_nt<4, 0><<<64, 512, 0, stream>>>(
          P, Vt + b * SE, l + b * S, nullptr, out + b * SE, S, E, 1.0f,
          0, 0, 0, 0, nullptr, E / BN, S / BM, 1, 1, 0);
    }
  }
}

// Round 7
// 515.573 us; speedup vs baseline: 1.0666x; 1.0666x over previous
//
#include <hip/hip_runtime.h>
#include <stdint.h>

// ---------------------------------------------------------------------------
// SelfAttention B=4 S=4096 E=1024, fp32 in/out, bf16 MFMA internally.
// Round 12 (over R11): revert QK split (R11: +34us, A/B inconclusive — both
// halves below the top-5 cutoff) and DELETE the explicit lgkmcnt(0) from
// PH_TAIL.
//  - R6 counters: PV = 1049 TF (MfmaUtil 43%), QK = 755 TF (32%) at both
//    tpb=1 and tpb=4. Phase model: the block's ds_read burst (up to 96 b128
//    in ph1/ph5) is force-drained by my explicit lgkmcnt(0) before ANY MFMA
//    issues (~768cy LDS serial + 155cy MFMA + barriers ~= observed 1228).
//  - The lgkmcnt(0) is correctness-redundant: the only lgkm ops are this
//    wave's own C-level ds_reads (compiler inserts counted per-use waits);
//    GLL staging is vmcnt-tracked; cross-wave safety = barrier + vmcnt(6)
//    ledger. Removing it lets each wave's MFMAs start as its own operands
//    land, overlapping MFMA with the tail of the block's LDS burst.
//  - Everything else identical to R10/R5 (8 LDS symbols, read-once frags,
//    persistent chaining, seamless stage stream, XCD-chunked tiles).
// ---------------------------------------------------------------------------

typedef unsigned short ushort_t;
typedef unsigned int uint_t;
typedef __attribute__((ext_vector_type(8))) short short8;     // 8 bf16 = 4 VGPRs
typedef __attribute__((ext_vector_type(4))) float f32x4;      // MFMA acc

__device__ inline ushort_t f2bf(float f) {
  union { float f; unsigned u; } v; v.f = f;
  unsigned r = v.u + 0x7fffu + ((v.u >> 16) & 1u);  // RNE
  return (ushort_t)(r >> 16);
}

// ---------------------------------------------------------------------------
__global__ __launch_bounds__(256) void zero_f32(float* __restrict__ p, int n) {
  int i = blockIdx.x * 256 + threadIdx.x;
  if (i < n) p[i] = 0.0f;
}

// fp32 -> bf16 conversion, float4 loads, exact-fit grid (n4 = n/4)
__global__ __launch_bounds__(256) void cvt_f32_bf16(
    const float* __restrict__ in, ushort_t* __restrict__ out, int n4) {
  int i = blockIdx.x * 256 + threadIdx.x;
  if (i < n4) {
    float4 v = ((const float4*)in)[i];
    ushort4 o;
    o.x = f2bf(v.x); o.y = f2bf(v.y); o.z = f2bf(v.z); o.w = f2bf(v.w);
    ((ushort4*)out)[i] = o;
  }
}

// ---------------------------------------------------------------------------
// NT GEMM: C[m][n] = f( scale * sum_k A[m][k]*B[n][k] )
// A: [M x K] row-major bf16. B: [N x K] row-major bf16. Batch z folded into
// the tile list (strides sA/sB/sC in elements).
// EPI: 1 = +bias[col] (bias = z ? aux2 : aux), bf16 out   (Q&K projections)
//      2 = +bias[row], bf16 out                           (Vt)
//      3 = exp(v), bf16 out, atomicAdd row sums into lsum[z*lstride+row]
//      4 = v * (1/aux[z*lstride+row]), fp32 out           (PV, normalize)
// ---------------------------------------------------------------------------
#define BM 256
#define BN 256
#define BK 64

template<int EPI>
__global__ __launch_bounds__(512, 2) void gemm_nt(
    const ushort_t* __restrict__ A, const ushort_t* __restrict__ B,
    const float* __restrict__ aux, const float* __restrict__ aux2,
    void* __restrict__ Cv,
    int K, int ldc, float scale, long sA, long sB, long sC,
    int lstride, float* __restrict__ lsum,
    int tn, int tm, int tz, int tpb) {
  // 8 distinct slot arrays: [128 rows x 64 cols] each, chunk-swizzled:
  // slot (r,c) holds global chunk c^(r&7). 8 x 16 KiB = 128 KiB.
  __shared__ ushort_t As00[128 * 64];  // buf0 half0
  __shared__ ushort_t As01[128 * 64];  // buf0 half1
  __shared__ ushort_t As10[128 * 64];  // buf1 half0
  __shared__ ushort_t As11[128 * 64];  // buf1 half1
  __shared__ ushort_t Bs00[128 * 64];
  __shared__ ushort_t Bs01[128 * 64];
  __shared__ ushort_t Bs10[128 * 64];
  __shared__ ushort_t Bs11[128 * 64];

  const int t = threadIdx.x;
  const int lane = t & 63;
  const int wave = t >> 6;
  const int wr = wave >> 2;          // 0..1 (M waves)
  const int wc = wave & 3;           // 0..3 (N waves)
  const int lr = lane & 15;          // fragment row (m or n)
  const int quad = lane >> 4;        // 0..3

  const int Kb = K * 2;              // row stride in bytes
  const int nkt = K / BK;            // K-tiles per output tile
  const int niter = nkt >> 1;

  // staging geometry: per half-tile (128x64), 512 thr x 2 x 16B; LDS dst is
  // LINEAR (global_load_lds requirement); src col pre-swizzled c^(r&7).
  const int srow = t >> 3;                        // 0..63 (2nd load adds 64)
  const int scol = ((t & 7) ^ (srow & 7)) << 3;   // swizzled src col (elems)

  // ---- tile list: XCD-chunked persistent mapping --------------------------
  const int NT = tn * tm * tz;
  const int tmn = tn * tm;
  const bool chunked = (gridDim.x == 256) && ((NT & 255) == 0);
  const int xcd = blockIdx.x & 7, wblk = blockIdx.x >> 3;
  const int cpx = NT >> 3;

  auto calc = [&](int i, int& m0_, int& n0_, long& z_, uint_t& oa_, uint_t& ob_) {
    const int lin = chunked ? (xcd * cpx + i * 32 + wblk)
                            : ((int)blockIdx.x + i * (int)gridDim.x);
    const int zz = lin / tmn;
    const int r = lin - zz * tmn;
    const int mi = r / tn;
    const int ni = r - mi * tn;
    m0_ = mi * BM; n0_ = ni * BN; z_ = zz;
    oa_ = (uint_t)(((size_t)zz * (size_t)sA + (size_t)(m0_ + srow) * K + scol) * 2);
    ob_ = (uint_t)(((size_t)zz * (size_t)sB + (size_t)(n0_ + srow) * K + scol) * 2);
  };

  int m0, n0, m0n, n0n;
  long z, zn;
  uint_t oA_cur, oB_cur, oA_nxt, oB_nxt;
  calc(0, m0, n0, z, oA_cur, oB_cur);
  bool have_next = (tpb > 1);
  if (have_next) calc(1, m0n, n0n, zn, oA_nxt, oB_nxt);
  else { m0n = m0; n0n = n0; zn = z; oA_nxt = oA_cur; oB_nxt = oB_cur; }

#define GLL(gp, lp) __builtin_amdgcn_global_load_lds( \
    (const __attribute__((address_space(1))) void*)(gp), \
    (__attribute__((address_space(3))) void*)(lp), 16, 0, 0)

  // j = K-tile index in the CURRENT tile's stream; j>=nkt -> next tile.
  // ARR: one of the 8 slot arrays; h: which 128-row half of the source tile.
#define STAGE_A(ARR, h, j) do { \
    const int j_ = (j); \
    const bool in_ = (j_ < nkt); \
    if (in_ || have_next) { \
      const uint_t o_ = (in_ ? (oA_cur + (uint_t)(j_ * 128)) \
                             : (oA_nxt + (uint_t)((j_ - nkt) * 128))) \
                        + (uint_t)((h) * 128 * Kb); \
      const char* g_ = (const char*)A + o_; \
      GLL(g_, &ARR[t * 8]); \
      GLL(g_ + (size_t)64 * Kb, &ARR[(512 + t) * 8]); } } while (0)

#define STAGE_B(ARR, h, j) do { \
    const int j_ = (j); \
    const bool in_ = (j_ < nkt); \
    if (in_ || have_next) { \
      const uint_t o_ = (in_ ? (oB_cur + (uint_t)(j_ * 128)) \
                             : (oB_nxt + (uint_t)((j_ - nkt) * 128))) \
                        + (uint_t)((h) * 128 * Kb); \
      const char* g_ = (const char*)B + o_; \
      GLL(g_, &ARR[t * 8]); \
      GLL(g_ + (size_t)64 * Kb, &ARR[(512 + t) * 8]); } } while (0)

  // LDS read offsets (elements). ks=1 flips chunk bit 2 -> offset ^ 32.
  int aoff[4], boff[2];
#pragma unroll
  for (int mi = 0; mi < 4; ++mi)
    aoff[mi] = (wr * 64 + mi * 16 + lr) * 64 + ((quad ^ (lr & 7)) << 3);
#pragma unroll
  for (int ni = 0; ni < 2; ++ni)
    boff[ni] = (wc * 32 + ni * 16 + lr) * 64 + ((quad ^ (lr & 7)) << 3);

  f32x4 acc[8][4] = {};
  short8 af[4][2];        // A fragments, current mh
  short8 bfr[2][2][2];    // [nh][ni][ks] — BOTH N-halves persist (read-once)

#define LDA(ARR) do { \
  _Pragma("unroll") for (int mi_ = 0; mi_ < 4; ++mi_) { \
    af[mi_][0] = *(const short8*)&ARR[aoff[mi_]]; \
    af[mi_][1] = *(const short8*)&ARR[aoff[mi_] ^ 32]; } } while (0)

#define LDB(ARR, nh) do { \
  _Pragma("unroll") for (int ni_ = 0; ni_ < 2; ++ni_) { \
    bfr[nh][ni_][0] = *(const short8*)&ARR[boff[ni_]]; \
    bfr[nh][ni_][1] = *(const short8*)&ARR[boff[ni_] ^ 32]; } } while (0)

#define MFMA16(mh, nh) do { \
  _Pragma("unroll") for (int mi_ = 0; mi_ < 4; ++mi_) \
  _Pragma("unroll") for (int ni_ = 0; ni_ < 2; ++ni_) { \
    acc[(mh) * 4 + mi_][(nh) * 2 + ni_] = __builtin_amdgcn_mfma_f32_16x16x32_bf16( \
        af[mi_][0], bfr[nh][ni_][0], acc[(mh) * 4 + mi_][(nh) * 2 + ni_], 0, 0, 0); \
    acc[(mh) * 4 + mi_][(nh) * 2 + ni_] = __builtin_amdgcn_mfma_f32_16x16x32_bf16( \
        af[mi_][1], bfr[nh][ni_][1], acc[(mh) * 4 + mi_][(nh) * 2 + ni_], 0, 0, 0); } } while (0)

// NOTE: no explicit lgkmcnt(0) — the only lgkm ops are this wave's own
// C-level ds_reads; the compiler inserts counted per-use waits, so MFMAs
// start as their operands land instead of after the block's full LDS burst.
#define PH_TAIL \
  __builtin_amdgcn_s_barrier(); \
  __builtin_amdgcn_s_setprio(1)

#define PH_END \
  __builtin_amdgcn_s_setprio(0); \
  __builtin_amdgcn_s_barrier()

#define VM6_BAR \
  __builtin_amdgcn_s_setprio(0); \
  asm volatile("s_waitcnt vmcnt(6)" ::: "memory"); \
  __builtin_amdgcn_s_barrier()

  // ---- prologue: kt0 {As00,Bs00,Bs01,As01}, kt1 {As10,Bs10,Bs11};
  //      kt1's As11 is staged at iter0-ph1.
  STAGE_A(As00, 0, 0); STAGE_B(Bs00, 0, 0); STAGE_B(Bs01, 1, 0); STAGE_A(As01, 1, 0);
  STAGE_A(As10, 0, 1); STAGE_B(Bs10, 0, 1); STAGE_B(Bs11, 1, 1);
  asm volatile("s_waitcnt vmcnt(6)" ::: "memory");   // kt0 fully resident
  __builtin_amdgcn_s_barrier();

  for (int tile = 0; tile < tpb; ++tile) {
    for (int itl = 0; itl < niter; ++itl) {
      const int T = itl * 2;

      // ===== buf0 (K-tile T) =====
      // ph1: read As00 + Bs00 | stage As11 <- A1(T+1)  (gap: read ph7 prev)
      LDA(As00); LDB(Bs00, 0);
      STAGE_A(As11, 1, T + 1);
      PH_TAIL; MFMA16(0, 0); PH_END;

      // ph2: read Bs01 | stage As00 <- A0(T+2)  (As00 last read ph1)
      LDB(Bs01, 1);
      STAGE_A(As00, 0, T + 2);
      PH_TAIL; MFMA16(0, 1); PH_END;

      // ph3: read As01 | stage Bs00 <- B0(T+2)  (Bs00 last read ph1)
      LDA(As01);
      STAGE_B(Bs00, 0, T + 2);
      PH_TAIL; MFMA16(1, 0); PH_END;

      // ph4: no reads | stage Bs01 <- B1(T+2)  (Bs01 last read ph2)
      STAGE_B(Bs01, 1, T + 2);
      PH_TAIL; MFMA16(1, 1);
      VM6_BAR;   // completes ...ph1 -> buf1 (T+1) fully resident

      // ===== buf1 (K-tile T+1) =====
      // ph5: read As10 + Bs10 | stage As01 <- A1(T+2)  (As01 last read ph3)
      LDA(As10); LDB(Bs10, 0);
      STAGE_A(As01, 1, T + 2);
      PH_TAIL; MFMA16(0, 0); PH_END;

      // ph6: read Bs11 | stage As10 <- A0(T+3)  (As10 last read ph5)
      LDB(Bs11, 1);
      STAGE_A(As10, 0, T + 3);
      PH_TAIL; MFMA16(0, 1); PH_END;

      // ph7: read As11 | stage Bs10 <- B0(T+3)  (Bs10 last read ph5)
      LDA(As11);
      STAGE_B(Bs10, 0, T + 3);
      PH_TAIL; MFMA16(1, 0); PH_END;

      // ph8: no reads | stage Bs11 <- B1(T+3)  (Bs11 last read ph6)
      STAGE_B(Bs11, 1, T + 3);
      PH_TAIL; MFMA16(1, 1);
      VM6_BAR;   // completes ...ph5 -> buf0 (T+2) fully resident
    }

    // ---- epilogue for tile (m0, n0, z). No LDS use; next tile's staging is
    // already in flight and lands underneath these VALU ops + stores.
    // C/D layout: col = lane&15, row = (lane>>4)*4 + reg [m89-verified]
    {
      const float* bias = (EPI == 1 && z) ? aux2 : aux;
#pragma unroll
      for (int fm = 0; fm < 8; ++fm) {
#pragma unroll
        for (int r = 0; r < 4; ++r) {
          const int row = m0 + (fm >> 2) * 128 + wr * 64 + (fm & 3) * 16 + quad * 4 + r;
          float rs = 0.0f, rl = 0.0f;
          if (EPI == 4) rl = 1.0f / bias[(size_t)z * lstride + row];
#pragma unroll
          for (int fn = 0; fn < 4; ++fn) {
            const int col = n0 + (fn >> 1) * 128 + wc * 32 + (fn & 1) * 16 + lr;
            const size_t off = (size_t)(z * sC) + (size_t)row * ldc + col;
            float v = acc[fm][fn][r] * scale;
            if (EPI == 1) {
              ((ushort_t*)Cv)[off] = f2bf(v + bias[col]);
            } else if (EPI == 2) {
              ((ushort_t*)Cv)[off] = f2bf(v + bias[row]);
            } else if (EPI == 3) {
              float e = __expf(v);
              rs += e;
              ((ushort_t*)Cv)[off] = f2bf(e);
            } else {  // EPI == 4
              ((float*)Cv)[off] = v * rl;
            }
          }
          if (EPI == 3) {
            rs += __shfl_xor(rs, 1);
            rs += __shfl_xor(rs, 2);
            rs += __shfl_xor(rs, 4);
            rs += __shfl_xor(rs, 8);
            if (lr == 0)
              atomicAdd(&lsum[(size_t)z * lstride + row], rs);
          }
        }
      }
    }

    // ---- tile switch: shift next->cur, compute tile+2, re-zero acc.
    if (tile + 1 < tpb) {
      m0 = m0n; n0 = n0n; z = zn; oA_cur = oA_nxt; oB_cur = oB_nxt;
      if (tile + 2 < tpb) calc(tile + 2, m0n, n0n, zn, oA_nxt, oB_nxt);
      have_next = (tile + 2 < tpb);
#pragma unroll
      for (int fm = 0; fm < 8; ++fm)
#pragma unroll
        for (int fn = 0; fn < 4; ++fn)
          acc[fm][fn] = (f32x4){0.0f, 0.0f, 0.0f, 0.0f};
    }
  }
}

// ---------------------------------------------------------------------------
extern "C" void kernel_launch(void* const* d_in, const int* in_sizes, int n_in,
                              void* d_out, int out_size, void* d_ws,
                              size_t ws_size, hipStream_t stream) {
  const float* X  = (const float*)d_in[0];
  const float* Wq = (const float*)d_in[1];
  const float* bq = (const float*)d_in[2];
  const float* Wk = (const float*)d_in[3];
  const float* bk = (const float*)d_in[4];
  const float* Wv = (const float*)d_in[5];
  const float* bv = (const float*)d_in[6];
  float* out = (float*)d_out;

  const int Bn = 4, S = 4096, E = 1024;
  const long SE  = (long)S * E;       //  4,194,304
  const long BSE = (long)Bn * SE;     // 16,777,216
  const long SS  = (long)S * S;       // 16,777,216
  const long EE  = (long)E * E;       //  1,048,576

  // Batched path: P holds all 4 batches (134.2 MB, aliases dead Xb + spare).
  const size_t need_batched =
      (size_t)(4 * SS + 3 * EE + 3 * BSE) * 2 + (size_t)Bn * S * 4;
  const bool batched = ws_size >= need_batched;

  const long front = batched ? 4 * SS : BSE;  // bf16 elems reserved at base
  ushort_t* Xb  = (ushort_t*)d_ws;    // [B*S, E]   (steps 1-3)
  ushort_t* P   = (ushort_t*)d_ws;    // scores: [B,S,S] batched / [S,S] fallback
  ushort_t* Wqb = (ushort_t*)d_ws + front;
  ushort_t* Wkb = Wqb + EE;
  ushort_t* Wvb = Wkb + EE;
  ushort_t* Qw  = Wvb + EE;           // [B*S, E]
  ushort_t* Kw  = Qw + BSE;           // [B*S, E]  (contiguous after Qw!)
  ushort_t* Vt  = Kw + BSE;           // [B, E, S]  (V transposed)
  float*    l   = (float*)(Vt + BSE); // [B*S] softmax row sums

  // 0) zero the row-sum accumulator (ws re-poisoned to 0xAA every launch)
  zero_f32<<<(Bn * S) / 256, 256, 0, stream>>>(l, Bn * S);

  // 1) fp32 -> bf16
  cvt_f32_bf16<<<(int)(BSE / 1024), 256, 0, stream>>>(X, Xb, (int)(BSE / 4));
  cvt_f32_bf16<<<(int)(EE / 1024), 256, 0, stream>>>(Wq, Wqb, (int)(EE / 4));
  cvt_f32_bf16<<<(int)(EE / 1024), 256, 0, stream>>>(Wk, Wkb, (int)(EE / 4));
  cvt_f32_bf16<<<(int)(EE / 1024), 256, 0, stream>>>(Wv, Wvb, (int)(EE / 4));

  // 2) Q = X·Wq^T + bq ; K = X·Wk^T + bk  (z folded: NT = 4*64*2 = 512, tpb=2)
  gemm_nt<1><<<256, 512, 0, stream>>>(
      Xb, Wqb, bq, bk, Qw, E, E, 1.0f, 0, EE, BSE, 0, nullptr,
      E / BN, Bn * S / BM, 2, 2);

  // 3) Vt[b][e][t] = Wv[e]·X[b][t] + bv[e]  (NT = 16*4*4 = 256, tpb=1)
  gemm_nt<2><<<256, 512, 0, stream>>>(
      Wvb, Xb, bv, nullptr, Vt, E, S, 1.0f, 0, SE, SE, 0, nullptr,
      S / BN, E / BM, Bn, 1);

  if (batched) {
    // 4) P = exp(Q·K^T / 32), l[row] += rowsum  (NT = 16*16*4 = 1024, tpb=4)
    gemm_nt<3><<<256, 512, 0, stream>>>(
        Qw, Kw, nullptr, nullptr, P, E, S, 0.03125f, SE, SE, SS, S, l,
        S / BN, S / BM, Bn, 4);
    // 5) out = (P·Vt^T) / l[row]  (NT = 4*16*4 = 256, tpb=1)
    gemm_nt<4><<<256, 512, 0, stream>>>(
        P, Vt, l, nullptr, out, S, E, 1.0f, SS, SE, SE, S, nullptr,
        E / BN, S / BM, Bn, 1);
  } else {
    // fallback: per-batch P (aliases dead Xb), stream-ordered reuse
    for (int b = 0; b < Bn; ++b) {
      gemm_nt<3><<<256, 512, 0, stream>>>(
          Qw + b * SE, Kw + b * SE, nullptr, nullptr, P, E, S, 0.03125f,
          0, 0, 0, 0, l + b * S, S / BN, S / BM, 1, 1);
      gemm_nt<4><<<64, 512, 0, stream>>>(
          P, Vt + b * SE, l + b * S, nullptr, out + b * SE, S, E, 1.0f,
          0, 0, 0, 0, nullptr, E / BN, S / BM, 1, 1);
    }
  }
}